// Round 5
// baseline (269.071 us; speedup 1.0000x reference)
//
#include <hip/hip_runtime.h>
#include <math.h>

#define BB 2
#define TT 2048
#define CC 1024
#define UU 1024
#define HH 16
#define DH 64
#define BT (BB*TT)

typedef __attribute__((ext_vector_type(8))) __bf16 bf16x8;
typedef __attribute__((ext_vector_type(4))) __bf16 bf16x4;
typedef __attribute__((ext_vector_type(4))) float f32x4;

#define GLL16(g, l) __builtin_amdgcn_global_load_lds( \
    (__attribute__((address_space(1))) const void*)(g), \
    (__attribute__((address_space(3))) void*)(l), 16, 0, 0)

// log2(e)/8 : folds the 1/sqrt(dh) scale and the exp->exp2 conversion
#define C2EXP 0.18033688011112042f
#define MBIAS 64.0f

// ---------------- fused rowsum-mask + fp32->bf16 cast of x ----------------
// kadd[row] = (sum(x_row)==0 ? -1e30 : 0) - 64   (additive softmax arg)
__global__ __launch_bounds__(256) void rowsum_cast(const float* __restrict__ x,
                                                   float* __restrict__ kadd,
                                                   __bf16* __restrict__ xb) {
    int row = blockIdx.x;
    int t = threadIdx.x;
    float4 v = *(const float4*)&x[(size_t)row * CC + t * 4];
    bf16x4 o;
    o[0] = (__bf16)v.x; o[1] = (__bf16)v.y; o[2] = (__bf16)v.z; o[3] = (__bf16)v.w;
    *(bf16x4*)&xb[(size_t)row * CC + t * 4] = o;
    float s = v.x + v.y + v.z + v.w;
#pragma unroll
    for (int off = 32; off; off >>= 1) s += __shfl_down(s, off, 64);
    __shared__ float red[4];
    int lane = t & 63, w = t >> 6;
    if (lane == 0) red[w] = s;
    __syncthreads();
    if (t == 0) {
        float tot = red[0] + red[1] + red[2] + red[3];
        kadd[row] = (tot == 0.f ? -1.0e30f : 0.f) - MBIAS;
    }
}

// ---------------- weight cast+transpose: W[k][n] fp32 -> Wt[n][k] bf16 ----------------
__global__ __launch_bounds__(256) void wcastT(const float* __restrict__ Wq,
                                              const float* __restrict__ Wk,
                                              const float* __restrict__ Wv,
                                              __bf16* __restrict__ Wt) {
    const float* W = blockIdx.z == 0 ? Wq : (blockIdx.z == 1 ? Wk : Wv);
    __bf16* Out = Wt + (size_t)blockIdx.z * CC * UU;
    __shared__ float tile[64][65];
    int n0 = blockIdx.x * 64, k0 = blockIdx.y * 64;
    int t = threadIdx.x;
    int r = t >> 4, c4 = (t & 15) * 4;
#pragma unroll
    for (int i = 0; i < 4; ++i) {
        float4 v = *(const float4*)&W[(size_t)(k0 + r + i * 16) * UU + n0 + c4];
        tile[r + i * 16][c4 + 0] = v.x; tile[r + i * 16][c4 + 1] = v.y;
        tile[r + i * 16][c4 + 2] = v.z; tile[r + i * 16][c4 + 3] = v.w;
    }
    __syncthreads();
#pragma unroll
    for (int i = 0; i < 4; ++i) {
        int nr = r + i * 16;
        bf16x4 o;
        o[0] = (__bf16)tile[c4 + 0][nr]; o[1] = (__bf16)tile[c4 + 1][nr];
        o[2] = (__bf16)tile[c4 + 2][nr]; o[3] = (__bf16)tile[c4 + 3][nr];
        *(bf16x4*)&Out[(size_t)(n0 + nr) * CC + k0 + c4] = o;
    }
}

// ---------------- QKV GEMM, bf16 MFMA, BK=64, XOR-swizzled LDS ----------------
__global__ __launch_bounds__(256) void qkv_mfma(
    const __bf16* __restrict__ xb, const __bf16* __restrict__ Wt_all,
    const float* __restrict__ bq, const float* __restrict__ bk,
    const float* __restrict__ bv,
    __bf16* __restrict__ Qo, __bf16* __restrict__ Ko, __bf16* __restrict__ VTo) {
    const int z = blockIdx.z;
    const __bf16* Wt = Wt_all + (size_t)z * CC * UU;
    const float* bias = z == 0 ? bq : (z == 1 ? bk : bv);

    const int n0 = blockIdx.x * 128, m0 = blockIdx.y * 128;
    const int t = threadIdx.x, w = t >> 6, lane = t & 63;
    const int quad = lane >> 4, nn = lane & 15;
    const int wr = w >> 1, wc = w & 1;

    __shared__ __bf16 smem[2 * 128 * 64];   // 32 KiB: As | Bs, Cs aliases front
    __bf16* As = smem;
    __bf16* Bs = smem + 128 * 64;

    f32x4 acc[4][4];
#pragma unroll
    for (int i = 0; i < 4; ++i)
#pragma unroll
        for (int j = 0; j < 4; ++j) acc[i][j] = (f32x4){0.f, 0.f, 0.f, 0.f};

    for (int k0 = 0; k0 < CC; k0 += 64) {
        __syncthreads();
#pragma unroll
        for (int i = 0; i < 4; ++i) {
            int c = i * 256 + t;
            int row = c >> 3;
            int gc = ((c & 7) ^ (row & 7)) * 8;
            GLL16(&xb[(size_t)(m0 + row) * CC + k0 + gc], &As[c * 8]);
            GLL16(&Wt[(size_t)(n0 + row) * CC + k0 + gc], &Bs[c * 8]);
        }
        __syncthreads();
#pragma unroll
        for (int kk = 0; kk < 2; ++kk) {
            bf16x8 af[4], bfr[4];
#pragma unroll
            for (int i = 0; i < 4; ++i) {
                int R = wr * 64 + i * 16 + nn;
                af[i] = *(const bf16x8*)&As[R * 64 + (((kk * 4 + quad) ^ (R & 7)) * 8)];
            }
#pragma unroll
            for (int j = 0; j < 4; ++j) {
                int R = wc * 64 + j * 16 + nn;
                bfr[j] = *(const bf16x8*)&Bs[R * 64 + (((kk * 4 + quad) ^ (R & 7)) * 8)];
            }
#pragma unroll
            for (int i = 0; i < 4; ++i)
#pragma unroll
                for (int j = 0; j < 4; ++j)
                    acc[i][j] = __builtin_amdgcn_mfma_f32_16x16x32_bf16(af[i], bfr[j], acc[i][j], 0, 0, 0);
        }
    }

    __bf16* cw = &smem[w * 1024];
    float bv4[4];
#pragma unroll
    for (int j = 0; j < 4; ++j) bv4[j] = bias[n0 + wc * 64 + j * 16 + nn];

    if (z < 2) {
        __bf16* Out = z == 0 ? Qo : Ko;
#pragma unroll
        for (int i = 0; i < 4; ++i) {
            __syncthreads();
#pragma unroll
            for (int j = 0; j < 4; ++j)
#pragma unroll
                for (int r = 0; r < 4; ++r)
                    cw[(quad * 4 + r) * 64 + j * 16 + nn] =
                        (__bf16)fmaxf(acc[i][j][r] + bv4[j], 0.f);
            __syncthreads();
            int rr = lane >> 2, cc = (lane & 3) * 16;
            bf16x8 v0 = *(const bf16x8*)&cw[rr * 64 + cc];
            bf16x8 v1 = *(const bf16x8*)&cw[rr * 64 + cc + 8];
            size_t o = (size_t)(m0 + wr * 64 + i * 16 + rr) * UU + n0 + wc * 64 + cc;
            *(bf16x8*)&Out[o] = v0;
            *(bf16x8*)&Out[o + 8] = v1;
        }
    } else {
#pragma unroll
        for (int i = 0; i < 4; ++i) {
            __syncthreads();
#pragma unroll
            for (int j = 0; j < 4; ++j)
#pragma unroll
                for (int r = 0; r < 4; ++r)
                    cw[(j * 16 + nn) * 16 + quad * 4 + r] =
                        (__bf16)fmaxf(acc[i][j][r] + bv4[j], 0.f);
            __syncthreads();
            bf16x8 v0 = *(const bf16x8*)&cw[lane * 16];
            bf16x8 v1 = *(const bf16x8*)&cw[lane * 16 + 8];
            size_t o = (size_t)(n0 + wc * 64 + lane) * BT + m0 + wr * 64 + i * 16;
            *(bf16x8*)&VTo[o] = v0;
            *(bf16x8*)&VTo[o + 8] = v1;
        }
    }
}

// ---------------- MFMA flash attention, split-K x2, GLL staging ----------------
// grid.x = 64: pair = bx>>1 (qt = 31-pair, big first), hf = bx&1 selects k-range half.
// Partial O (bf16, unnormalized) + partial l per (bh, q-row); merged in ln_merge.
// LDS 24 KiB -> 6 blocks/CU.
__global__ __launch_bounds__(256, 6) void attn_mfma(
    const __bf16* __restrict__ Q, const __bf16* __restrict__ K,
    const __bf16* __restrict__ Vt, const float* __restrict__ kadd,
    __bf16* __restrict__ O0, __bf16* __restrict__ O1,
    float* __restrict__ L0, float* __restrict__ L1) {
    const int pair = blockIdx.x >> 1, hf = blockIdx.x & 1;
    const int qt = 31 - pair;
    const int bh = blockIdx.y, b = bh >> 4, h = bh & 15;
    const int col0 = h * 64, rowbase = b * TT, q0 = qt * 64;
    const int nk = qt + 1, chalf = (nk + 1) >> 1;
    const int klo = hf ? chalf : 0, khi = hf ? nk : chalf;
    __bf16* Op = hf ? O1 : O0;
    float* Lp = hf ? L1 : L0;

    const int t = threadIdx.x;
    const int w = t >> 6, lane = t & 63, quad = lane >> 4, nn = lane & 15;
    const int s7 = nn & 7;

    __shared__ __align__(16) __bf16 ks[64 * 64];
    __shared__ __align__(16) __bf16 vt[64 * 64];
    __shared__ __align__(16) __bf16 ps[64 * 64];   // Q staging, then P (wave-private strips)

    // stage Q tile (swizzled) via global_load_lds
    {
        int c0 = t, c1 = 256 + t;
        int r0 = c0 >> 3, g0 = (c0 & 7) ^ (r0 & 7);
        int r1 = c1 >> 3, g1 = (c1 & 7) ^ (r1 & 7);
        GLL16(&Q[(size_t)(rowbase + q0 + r0) * UU + col0 + g0 * 8], &ps[c0 * 8]);
        GLL16(&Q[(size_t)(rowbase + q0 + r1) * UU + col0 + g1 * 8], &ps[c1 * 8]);
    }
    __syncthreads();
    const int arow = 16 * w + nn;
    bf16x8 aq0 = *(const bf16x8*)&ps[arow * 64 + ((quad ^ s7) * 8)];
    bf16x8 aq1 = *(const bf16x8*)&ps[arow * 64 + (((4 + quad) ^ s7) * 8)];

    float lpart[4] = {0.f, 0.f, 0.f, 0.f};
    f32x4 oc[4];
#pragma unroll
    for (int dt = 0; dt < 4; ++dt) oc[dt] = (f32x4){0.f, 0.f, 0.f, 0.f};
    const int rowl = 16 * w + quad * 4;

    for (int kt = klo; kt < khi; ++kt) {
        const int k0 = kt * 64;
        __syncthreads();   // prior-iter ks/vt reads done before overwrite
        {
            int c0 = t, c1 = 256 + t;
            int r0 = c0 >> 3, g0 = (c0 & 7) ^ (r0 & 7);
            int r1 = c1 >> 3, g1 = (c1 & 7) ^ (r1 & 7);
            GLL16(&K[(size_t)(rowbase + k0 + r0) * UU + col0 + g0 * 8], &ks[c0 * 8]);
            GLL16(&K[(size_t)(rowbase + k0 + r1) * UU + col0 + g1 * 8], &ks[c1 * 8]);
            GLL16(&Vt[(size_t)(col0 + r0) * BT + rowbase + k0 + g0 * 8], &vt[c0 * 8]);
            GLL16(&Vt[(size_t)(col0 + r1) * BT + rowbase + k0 + g1 * 8], &vt[c1 * 8]);
        }
        float ka0 = kadd[rowbase + k0 + nn];
        float ka1 = kadd[rowbase + k0 + 16 + nn];
        float ka2 = kadd[rowbase + k0 + 32 + nn];
        float ka3 = kadd[rowbase + k0 + 48 + nn];
        __syncthreads();   // vmcnt drain -> staged K/V visible

        const bool diag = (kt == qt);
#pragma unroll
        for (int ct = 0; ct < 4; ++ct) {
            int krow = ct * 16 + nn;
            bf16x8 b0 = *(const bf16x8*)&ks[krow * 64 + ((quad ^ s7) * 8)];
            bf16x8 b1 = *(const bf16x8*)&ks[krow * 64 + (((4 + quad) ^ s7) * 8)];
            f32x4 s = (f32x4){0.f, 0.f, 0.f, 0.f};
            s = __builtin_amdgcn_mfma_f32_16x16x32_bf16(aq0, b0, s, 0, 0, 0);
            s = __builtin_amdgcn_mfma_f32_16x16x32_bf16(aq1, b1, s, 0, 0, 0);
            float ka = ct == 0 ? ka0 : ct == 1 ? ka1 : ct == 2 ? ka2 : ka3;
            int pg = ct * 2 + (nn >> 3);   // column chunk of this lane's P values
#pragma unroll
            for (int r = 0; r < 4; ++r) {
                float arg = fmaf(s[r], C2EXP, ka);
                if (diag && krow > rowl + r) arg = -1.0e30f;
                float p = exp2f(arg);
                lpart[r] += p;
                int prow = rowl + r;
                ps[prow * 64 + ((pg ^ (prow & 7)) * 8) + s7] = (__bf16)p;
            }
        }
        // P fragments (wave-private strip; same-wave DS ordering, no barrier)
        bf16x8 ap0 = *(const bf16x8*)&ps[arow * 64 + ((quad ^ s7) * 8)];
        bf16x8 ap1 = *(const bf16x8*)&ps[arow * 64 + (((4 + quad) ^ s7) * 8)];
#pragma unroll
        for (int dt = 0; dt < 4; ++dt) {
            int vrow = dt * 16 + nn;
            bf16x8 b0 = *(const bf16x8*)&vt[vrow * 64 + ((quad ^ s7) * 8)];
            bf16x8 b1 = *(const bf16x8*)&vt[vrow * 64 + (((4 + quad) ^ s7) * 8)];
            oc[dt] = __builtin_amdgcn_mfma_f32_16x16x32_bf16(ap0, b0, oc[dt], 0, 0, 0);
            oc[dt] = __builtin_amdgcn_mfma_f32_16x16x32_bf16(ap1, b1, oc[dt], 0, 0, 0);
        }
    }

    // epilogue: store partial l and unnormalized partial O (bf16)
#pragma unroll
    for (int r = 0; r < 4; ++r) {
        float l = lpart[r];
        l += __shfl_xor(l, 1, 64);
        l += __shfl_xor(l, 2, 64);
        l += __shfl_xor(l, 4, 64);
        l += __shfl_xor(l, 8, 64);
        int qrow = q0 + 16 * w + quad * 4 + r;
        if (nn == 0) Lp[(size_t)bh * TT + qrow] = l;
        size_t ob = (size_t)(rowbase + qrow) * UU + col0;
#pragma unroll
        for (int dt = 0; dt < 4; ++dt)
            Op[ob + dt * 16 + nn] = (__bf16)oc[dt][r];
    }
}

// ---------------- merge partials + residual + layernorm ----------------
__global__ __launch_bounds__(256) void ln_merge(
    const __bf16* __restrict__ O0, const __bf16* __restrict__ O1,
    const float* __restrict__ L0, const float* __restrict__ L1,
    const float* __restrict__ kadd, const float* __restrict__ x,
    const float* __restrict__ gamma, const float* __restrict__ beta,
    float* __restrict__ out) {
    int row = blockIdx.x;                  // b*TT + tq
    int b = row >> 11, tq = row & (TT - 1);
    size_t base = (size_t)row * UU;
    int t = threadIdx.x, h = t >> 4;
    size_t li = (size_t)(b * 16 + h) * TT + tq;
    float l = L0[li] + L1[li];
    float qsel = (kadd[row] < -1.0e29f) ? 0.f : 1.f;
    float mult = qsel / fmaxf(l, 1e-37f);
    bf16x4 a0 = *(const bf16x4*)&O0[base + t * 4];
    bf16x4 a1 = *(const bf16x4*)&O1[base + t * 4];
    float4 xv = *(const float4*)&x[base + t * 4];
    float v0 = ((float)a0[0] + (float)a1[0]) * mult + xv.x;
    float v1 = ((float)a0[1] + (float)a1[1]) * mult + xv.y;
    float v2 = ((float)a0[2] + (float)a1[2]) * mult + xv.z;
    float v3 = ((float)a0[3] + (float)a1[3]) * mult + xv.w;
    float s1 = v0 + v1 + v2 + v3;
    float s2 = v0 * v0 + v1 * v1 + v2 * v2 + v3 * v3;
#pragma unroll
    for (int off = 32; off; off >>= 1) {
        s1 += __shfl_down(s1, off, 64);
        s2 += __shfl_down(s2, off, 64);
    }
    __shared__ float r1[4], r2[4];
    int lane = t & 63, w = t >> 6;
    if (lane == 0) { r1[w] = s1; r2[w] = s2; }
    __syncthreads();
    s1 = r1[0] + r1[1] + r1[2] + r1[3];
    s2 = r2[0] + r2[1] + r2[2] + r2[3];
    float mean = s1 * (1.0f / 1024.0f);
    float var = s2 * (1.0f / 1024.0f) - mean * mean;
    float rstd = rsqrtf(var + 1e-8f);
    float4 g = *(const float4*)&gamma[t * 4];
    float4 be = *(const float4*)&beta[t * 4];
    float4 ores;
    ores.x = g.x * (v0 - mean) * rstd + be.x;
    ores.y = g.y * (v1 - mean) * rstd + be.y;
    ores.z = g.z * (v2 - mean) * rstd + be.z;
    ores.w = g.w * (v3 - mean) * rstd + be.w;
    *(float4*)&out[base + t * 4] = ores;
}

extern "C" void kernel_launch(void* const* d_in, const int* in_sizes, int n_in,
                              void* d_out, int out_size, void* d_ws, size_t ws_size,
                              hipStream_t stream) {
    const float* x     = (const float*)d_in[0];
    const float* Wq    = (const float*)d_in[1];
    const float* bq    = (const float*)d_in[2];
    const float* Wk    = (const float*)d_in[3];
    const float* bk    = (const float*)d_in[4];
    const float* Wv    = (const float*)d_in[5];
    const float* bv    = (const float*)d_in[6];
    const float* gamma = (const float*)d_in[7];
    const float* beta  = (const float*)d_in[8];
    float* out = (float*)d_out;

    char* wsb = (char*)d_ws;
    const size_t MB = 1024ull * 1024;
    __bf16* xb = (__bf16*)(wsb);                 // 0..8 MiB   (dead after qkv)
    __bf16* Wt = (__bf16*)(wsb + 8 * MB);        // 8..14 MiB  (dead after qkv)
    __bf16* O0 = (__bf16*)(wsb);                 // 0..8 MiB   (aliases xb)
    __bf16* O1 = (__bf16*)(wsb + 8 * MB);        // 8..16 MiB  (aliases Wt + spare)
    __bf16* Qb = (__bf16*)(wsb + 16 * MB);       // 8 MiB
    __bf16* Kb = (__bf16*)(wsb + 24 * MB);       // 8 MiB
    __bf16* Vt = (__bf16*)(wsb + 32 * MB);       // 8 MiB
    float* kadd = (float*)(wsb + 40 * MB);       // 16 KiB
    float* L0 = (float*)(wsb + 40 * MB + 16 * 1024);           // 512 KiB
    float* L1 = (float*)(wsb + 40 * MB + 16 * 1024 + 512 * 1024); // 512 KiB

    rowsum_cast<<<dim3(BT), dim3(256), 0, stream>>>(x, kadd, xb);
    wcastT<<<dim3(16, 16, 3), dim3(256), 0, stream>>>(Wq, Wk, Wv, Wt);
    qkv_mfma<<<dim3(UU / 128, BT / 128, 3), dim3(256), 0, stream>>>(
        xb, Wt, bq, bk, bv, Qb, Kb, Vt);
    attn_mfma<<<dim3(64, BB * HH), dim3(256), 0, stream>>>(
        Qb, Kb, Vt, kadd, O0, O1, L0, L1);
    ln_merge<<<dim3(BT), dim3(256), 0, stream>>>(
        O0, O1, L0, L1, kadd, x, gamma, beta, out);
}

// Round 6
// 214.661 us; speedup vs baseline: 1.2535x; 1.2535x over previous
//
#include <hip/hip_runtime.h>
#include <math.h>

#define BB 2
#define TT 2048
#define CC 1024
#define UU 1024
#define HH 16
#define DH 64
#define BT (BB*TT)

typedef __attribute__((ext_vector_type(8))) __bf16 bf16x8;
typedef __attribute__((ext_vector_type(4))) __bf16 bf16x4;
typedef __attribute__((ext_vector_type(4))) float f32x4;

#define GLL16(g, l) __builtin_amdgcn_global_load_lds( \
    (__attribute__((address_space(1))) const void*)(g), \
    (__attribute__((address_space(3))) void*)(l), 16, 0, 0)

// log2(e)/8 : folds the 1/sqrt(dh) scale and the exp->exp2 conversion
#define C2EXP 0.18033688011112042f
#define MBIAS 64.0f

// ---------------- fused rowsum-mask + fp32->bf16 cast of x ----------------
__global__ __launch_bounds__(256) void rowsum_cast(const float* __restrict__ x,
                                                   float* __restrict__ kadd,
                                                   __bf16* __restrict__ xb) {
    int row = blockIdx.x;
    int t = threadIdx.x;
    float4 v = *(const float4*)&x[(size_t)row * CC + t * 4];
    bf16x4 o;
    o[0] = (__bf16)v.x; o[1] = (__bf16)v.y; o[2] = (__bf16)v.z; o[3] = (__bf16)v.w;
    *(bf16x4*)&xb[(size_t)row * CC + t * 4] = o;
    float s = v.x + v.y + v.z + v.w;
#pragma unroll
    for (int off = 32; off; off >>= 1) s += __shfl_down(s, off, 64);
    __shared__ float red[4];
    int lane = t & 63, w = t >> 6;
    if (lane == 0) red[w] = s;
    __syncthreads();
    if (t == 0) {
        float tot = red[0] + red[1] + red[2] + red[3];
        kadd[row] = (tot == 0.f ? -1.0e30f : 0.f) - MBIAS;
    }
}

// ---------------- weight cast+transpose: W[k][n] fp32 -> Wt[n][k] bf16 ----------------
__global__ __launch_bounds__(256) void wcastT(const float* __restrict__ Wq,
                                              const float* __restrict__ Wk,
                                              const float* __restrict__ Wv,
                                              __bf16* __restrict__ Wt) {
    const float* W = blockIdx.z == 0 ? Wq : (blockIdx.z == 1 ? Wk : Wv);
    __bf16* Out = Wt + (size_t)blockIdx.z * CC * UU;
    __shared__ float tile[64][65];
    int n0 = blockIdx.x * 64, k0 = blockIdx.y * 64;
    int t = threadIdx.x;
    int r = t >> 4, c4 = (t & 15) * 4;
#pragma unroll
    for (int i = 0; i < 4; ++i) {
        float4 v = *(const float4*)&W[(size_t)(k0 + r + i * 16) * UU + n0 + c4];
        tile[r + i * 16][c4 + 0] = v.x; tile[r + i * 16][c4 + 1] = v.y;
        tile[r + i * 16][c4 + 2] = v.z; tile[r + i * 16][c4 + 3] = v.w;
    }
    __syncthreads();
#pragma unroll
    for (int i = 0; i < 4; ++i) {
        int nr = r + i * 16;
        bf16x4 o;
        o[0] = (__bf16)tile[c4 + 0][nr]; o[1] = (__bf16)tile[c4 + 1][nr];
        o[2] = (__bf16)tile[c4 + 2][nr]; o[3] = (__bf16)tile[c4 + 3][nr];
        *(bf16x4*)&Out[(size_t)(n0 + nr) * CC + k0 + c4] = o;
    }
}

// ---------------- QKV GEMM, bf16 MFMA, BK=64, XOR-swizzled LDS ----------------
__global__ __launch_bounds__(256) void qkv_mfma(
    const __bf16* __restrict__ xb, const __bf16* __restrict__ Wt_all,
    const float* __restrict__ bq, const float* __restrict__ bk,
    const float* __restrict__ bv,
    __bf16* __restrict__ Qo, __bf16* __restrict__ Ko, __bf16* __restrict__ VTo) {
    const int z = blockIdx.z;
    const __bf16* Wt = Wt_all + (size_t)z * CC * UU;
    const float* bias = z == 0 ? bq : (z == 1 ? bk : bv);

    const int n0 = blockIdx.x * 128, m0 = blockIdx.y * 128;
    const int t = threadIdx.x, w = t >> 6, lane = t & 63;
    const int quad = lane >> 4, nn = lane & 15;
    const int wr = w >> 1, wc = w & 1;

    __shared__ __bf16 smem[2 * 128 * 64];   // 32 KiB: As | Bs, Cs aliases front
    __bf16* As = smem;
    __bf16* Bs = smem + 128 * 64;

    f32x4 acc[4][4];
#pragma unroll
    for (int i = 0; i < 4; ++i)
#pragma unroll
        for (int j = 0; j < 4; ++j) acc[i][j] = (f32x4){0.f, 0.f, 0.f, 0.f};

    for (int k0 = 0; k0 < CC; k0 += 64) {
        __syncthreads();
#pragma unroll
        for (int i = 0; i < 4; ++i) {
            int c = i * 256 + t;
            int row = c >> 3;
            int gc = ((c & 7) ^ (row & 7)) * 8;
            GLL16(&xb[(size_t)(m0 + row) * CC + k0 + gc], &As[c * 8]);
            GLL16(&Wt[(size_t)(n0 + row) * CC + k0 + gc], &Bs[c * 8]);
        }
        __syncthreads();
#pragma unroll
        for (int kk = 0; kk < 2; ++kk) {
            bf16x8 af[4], bfr[4];
#pragma unroll
            for (int i = 0; i < 4; ++i) {
                int R = wr * 64 + i * 16 + nn;
                af[i] = *(const bf16x8*)&As[R * 64 + (((kk * 4 + quad) ^ (R & 7)) * 8)];
            }
#pragma unroll
            for (int j = 0; j < 4; ++j) {
                int R = wc * 64 + j * 16 + nn;
                bfr[j] = *(const bf16x8*)&Bs[R * 64 + (((kk * 4 + quad) ^ (R & 7)) * 8)];
            }
#pragma unroll
            for (int i = 0; i < 4; ++i)
#pragma unroll
                for (int j = 0; j < 4; ++j)
                    acc[i][j] = __builtin_amdgcn_mfma_f32_16x16x32_bf16(af[i], bfr[j], acc[i][j], 0, 0, 0);
        }
    }

    __bf16* cw = &smem[w * 1024];
    float bv4[4];
#pragma unroll
    for (int j = 0; j < 4; ++j) bv4[j] = bias[n0 + wc * 64 + j * 16 + nn];

    if (z < 2) {
        __bf16* Out = z == 0 ? Qo : Ko;
#pragma unroll
        for (int i = 0; i < 4; ++i) {
            __syncthreads();
#pragma unroll
            for (int j = 0; j < 4; ++j)
#pragma unroll
                for (int r = 0; r < 4; ++r)
                    cw[(quad * 4 + r) * 64 + j * 16 + nn] =
                        (__bf16)fmaxf(acc[i][j][r] + bv4[j], 0.f);
            __syncthreads();
            int rr = lane >> 2, cc = (lane & 3) * 16;
            bf16x8 v0 = *(const bf16x8*)&cw[rr * 64 + cc];
            bf16x8 v1 = *(const bf16x8*)&cw[rr * 64 + cc + 8];
            size_t o = (size_t)(m0 + wr * 64 + i * 16 + rr) * UU + n0 + wc * 64 + cc;
            *(bf16x8*)&Out[o] = v0;
            *(bf16x8*)&Out[o + 8] = v1;
        }
    } else {
#pragma unroll
        for (int i = 0; i < 4; ++i) {
            __syncthreads();
#pragma unroll
            for (int j = 0; j < 4; ++j)
#pragma unroll
                for (int r = 0; r < 4; ++r)
                    cw[(j * 16 + nn) * 16 + quad * 4 + r] =
                        (__bf16)fmaxf(acc[i][j][r] + bv4[j], 0.f);
            __syncthreads();
            bf16x8 v0 = *(const bf16x8*)&cw[lane * 16];
            bf16x8 v1 = *(const bf16x8*)&cw[lane * 16 + 8];
            size_t o = (size_t)(n0 + wc * 64 + lane) * BT + m0 + wr * 64 + i * 16;
            *(bf16x8*)&VTo[o] = v0;
            *(bf16x8*)&VTo[o + 8] = v1;
        }
    }
}

// ---------------- MFMA flash attention, K/V double-buffered GLL staging ----------------
// one block per (q-tile 64, b*h), qt descending. 4 waves, wave w owns rows [16w,16w+16).
// LDS: ps 8K + ks 2x8K + vt 2x8K = 40 KiB -> 4 blocks/CU.
__global__ __launch_bounds__(256, 4) void attn_mfma(
    const __bf16* __restrict__ Q, const __bf16* __restrict__ K,
    const __bf16* __restrict__ Vt, const float* __restrict__ kadd,
    float* __restrict__ O) {
    const int qt = 31 - blockIdx.x;           // big-work blocks dispatch first
    const int bh = blockIdx.y, b = bh >> 4, h = bh & 15;
    const int col0 = h * 64, rowbase = b * TT, q0 = qt * 64;

    const int t = threadIdx.x;
    const int w = t >> 6, lane = t & 63, quad = lane >> 4, nn = lane & 15;
    const int s7 = nn & 7;

    __shared__ __align__(16) __bf16 ks[2][64 * 64];
    __shared__ __align__(16) __bf16 vt[2][64 * 64];
    __shared__ __align__(16) __bf16 ps[64 * 64];   // Q staging, then P (wave-private strips)

    const int c0 = t, c1 = 256 + t;
    const int r0 = c0 >> 3, g0 = ((c0 & 7) ^ (r0 & 7)) * 8;
    const int r1 = c1 >> 3, g1 = ((c1 & 7) ^ (r1 & 7)) * 8;

    // stage Q tile (swizzled) + first K/V tile (buffer 0)
    GLL16(&Q[(size_t)(rowbase + q0 + r0) * UU + col0 + g0], &ps[c0 * 8]);
    GLL16(&Q[(size_t)(rowbase + q0 + r1) * UU + col0 + g1], &ps[c1 * 8]);
    GLL16(&K[(size_t)(rowbase + r0) * UU + col0 + g0], &ks[0][c0 * 8]);
    GLL16(&K[(size_t)(rowbase + r1) * UU + col0 + g1], &ks[0][c1 * 8]);
    GLL16(&Vt[(size_t)(col0 + r0) * BT + rowbase + g0], &vt[0][c0 * 8]);
    GLL16(&Vt[(size_t)(col0 + r1) * BT + rowbase + g1], &vt[0][c1 * 8]);
    __syncthreads();   // vmcnt drain: Q + tile 0 visible

    const int arow = 16 * w + nn;
    bf16x8 aq0 = *(const bf16x8*)&ps[arow * 64 + ((quad ^ s7) * 8)];
    bf16x8 aq1 = *(const bf16x8*)&ps[arow * 64 + (((4 + quad) ^ s7) * 8)];

    float lpart[4] = {0.f, 0.f, 0.f, 0.f};
    f32x4 oc[4];
#pragma unroll
    for (int dt = 0; dt < 4; ++dt) oc[dt] = (f32x4){0.f, 0.f, 0.f, 0.f};
    const int rowl = 16 * w + quad * 4;

    for (int kt = 0; kt <= qt; ++kt) {
        const int cur = kt & 1;
        const int k0 = kt * 64;
        // prefetch next K/V tile into the other buffer (overlaps this iter's compute)
        if (kt < qt) {
            const int kn = k0 + 64;
            GLL16(&K[(size_t)(rowbase + kn + r0) * UU + col0 + g0], &ks[cur ^ 1][c0 * 8]);
            GLL16(&K[(size_t)(rowbase + kn + r1) * UU + col0 + g1], &ks[cur ^ 1][c1 * 8]);
            GLL16(&Vt[(size_t)(col0 + r0) * BT + rowbase + kn + g0], &vt[cur ^ 1][c0 * 8]);
            GLL16(&Vt[(size_t)(col0 + r1) * BT + rowbase + kn + g1], &vt[cur ^ 1][c1 * 8]);
        }
        float ka0 = kadd[rowbase + k0 + nn];
        float ka1 = kadd[rowbase + k0 + 16 + nn];
        float ka2 = kadd[rowbase + k0 + 32 + nn];
        float ka3 = kadd[rowbase + k0 + 48 + nn];

        const bool diag = (kt == qt);
        const __bf16* ksc = ks[cur];
        const __bf16* vtc = vt[cur];
#pragma unroll
        for (int ct = 0; ct < 4; ++ct) {
            int krow = ct * 16 + nn;
            bf16x8 b0 = *(const bf16x8*)&ksc[krow * 64 + ((quad ^ s7) * 8)];
            bf16x8 b1 = *(const bf16x8*)&ksc[krow * 64 + (((4 + quad) ^ s7) * 8)];
            f32x4 s = (f32x4){0.f, 0.f, 0.f, 0.f};
            s = __builtin_amdgcn_mfma_f32_16x16x32_bf16(aq0, b0, s, 0, 0, 0);
            s = __builtin_amdgcn_mfma_f32_16x16x32_bf16(aq1, b1, s, 0, 0, 0);
            float ka = ct == 0 ? ka0 : ct == 1 ? ka1 : ct == 2 ? ka2 : ka3;
            int pg = ct * 2 + (nn >> 3);
#pragma unroll
            for (int r = 0; r < 4; ++r) {
                float arg = fmaf(s[r], C2EXP, ka);
                if (diag && krow > rowl + r) arg = -1.0e30f;
                float p = exp2f(arg);
                lpart[r] += p;
                int prow = rowl + r;
                ps[prow * 64 + ((pg ^ (prow & 7)) * 8) + s7] = (__bf16)p;
            }
        }
        // P fragments (wave-private strip; same-wave DS ordering, no barrier)
        bf16x8 ap0 = *(const bf16x8*)&ps[arow * 64 + ((quad ^ s7) * 8)];
        bf16x8 ap1 = *(const bf16x8*)&ps[arow * 64 + (((4 + quad) ^ s7) * 8)];
#pragma unroll
        for (int dt = 0; dt < 4; ++dt) {
            int vrow = dt * 16 + nn;
            bf16x8 b0 = *(const bf16x8*)&vtc[vrow * 64 + ((quad ^ s7) * 8)];
            bf16x8 b1 = *(const bf16x8*)&vtc[vrow * 64 + (((4 + quad) ^ s7) * 8)];
            oc[dt] = __builtin_amdgcn_mfma_f32_16x16x32_bf16(ap0, b0, oc[dt], 0, 0, 0);
            oc[dt] = __builtin_amdgcn_mfma_f32_16x16x32_bf16(ap1, b1, oc[dt], 0, 0, 0);
        }
        __syncthreads();   // all waves done with buf[cur]; prefetch into buf[cur^1] drained
    }

    // epilogue: reduce l across the 16 column-lanes, /l, query mask, store
#pragma unroll
    for (int r = 0; r < 4; ++r) {
        float l = lpart[r];
        l += __shfl_xor(l, 1, 64);
        l += __shfl_xor(l, 2, 64);
        l += __shfl_xor(l, 4, 64);
        l += __shfl_xor(l, 8, 64);
        int grow = rowbase + q0 + 16 * w + quad * 4 + r;
        float qsel = (kadd[grow] < -1.0e29f) ? 0.f : 1.f;
        float mult = qsel / fmaxf(l, 1e-37f);
#pragma unroll
        for (int dt = 0; dt < 4; ++dt)
            O[(size_t)grow * UU + col0 + dt * 16 + nn] = oc[dt][r] * mult;
    }
}

// ---------------- residual + layernorm ----------------
__global__ __launch_bounds__(256) void ln_kernel(
    const float* __restrict__ O, const float* __restrict__ x,
    const float* __restrict__ gamma, const float* __restrict__ beta,
    float* __restrict__ out) {
    int row = blockIdx.x;
    size_t base = (size_t)row * UU;
    int t = threadIdx.x;
    float4 ov = *(const float4*)&O[base + t * 4];
    float4 xv = *(const float4*)&x[base + t * 4];
    float v0 = ov.x + xv.x, v1 = ov.y + xv.y, v2 = ov.z + xv.z, v3 = ov.w + xv.w;
    float s1 = v0 + v1 + v2 + v3;
    float s2 = v0 * v0 + v1 * v1 + v2 * v2 + v3 * v3;
#pragma unroll
    for (int off = 32; off; off >>= 1) {
        s1 += __shfl_down(s1, off, 64);
        s2 += __shfl_down(s2, off, 64);
    }
    __shared__ float r1[4], r2[4];
    int lane = t & 63, w = t >> 6;
    if (lane == 0) { r1[w] = s1; r2[w] = s2; }
    __syncthreads();
    s1 = r1[0] + r1[1] + r1[2] + r1[3];
    s2 = r2[0] + r2[1] + r2[2] + r2[3];
    float mean = s1 * (1.0f / 1024.0f);
    float var = s2 * (1.0f / 1024.0f) - mean * mean;
    float rstd = rsqrtf(var + 1e-8f);
    float4 g = *(const float4*)&gamma[t * 4];
    float4 be = *(const float4*)&beta[t * 4];
    float4 ores;
    ores.x = g.x * (v0 - mean) * rstd + be.x;
    ores.y = g.y * (v1 - mean) * rstd + be.y;
    ores.z = g.z * (v2 - mean) * rstd + be.z;
    ores.w = g.w * (v3 - mean) * rstd + be.w;
    *(float4*)&out[base + t * 4] = ores;
}

extern "C" void kernel_launch(void* const* d_in, const int* in_sizes, int n_in,
                              void* d_out, int out_size, void* d_ws, size_t ws_size,
                              hipStream_t stream) {
    const float* x     = (const float*)d_in[0];
    const float* Wq    = (const float*)d_in[1];
    const float* bq    = (const float*)d_in[2];
    const float* Wk    = (const float*)d_in[3];
    const float* bk    = (const float*)d_in[4];
    const float* Wv    = (const float*)d_in[5];
    const float* bv    = (const float*)d_in[6];
    const float* gamma = (const float*)d_in[7];
    const float* beta  = (const float*)d_in[8];
    float* out = (float*)d_out;

    char* wsb = (char*)d_ws;
    const size_t MB = 1024ull * 1024;
    __bf16* xb = (__bf16*)(wsb);                 // 0..8 MiB   (dead after qkv)
    __bf16* Wt = (__bf16*)(wsb + 8 * MB);        // 8..14 MiB  (dead after qkv)
    float*  O  = (float*)(wsb);                  // 0..16 MiB  (aliases xb+Wt)
    __bf16* Qb = (__bf16*)(wsb + 16 * MB);       // 8 MiB
    __bf16* Kb = (__bf16*)(wsb + 24 * MB);       // 8 MiB
    __bf16* Vt = (__bf16*)(wsb + 32 * MB);       // 8 MiB
    float* kadd = (float*)(wsb + 40 * MB);       // 16 KiB

    rowsum_cast<<<dim3(BT), dim3(256), 0, stream>>>(x, kadd, xb);
    wcastT<<<dim3(16, 16, 3), dim3(256), 0, stream>>>(Wq, Wk, Wv, Wt);
    qkv_mfma<<<dim3(UU / 128, BT / 128, 3), dim3(256), 0, stream>>>(
        xb, Wt, bq, bk, bv, Qb, Kb, Vt);
    attn_mfma<<<dim3(32, BB * HH), dim3(256), 0, stream>>>(Qb, Kb, Vt, kadd, O);
    ln_kernel<<<dim3(BT), dim3(256), 0, stream>>>(O, x, gamma, beta, out);
}